// Round 1
// baseline (604.921 us; speedup 1.0000x reference)
//
#include <hip/hip_runtime.h>
#include <stdint.h>

#define DIM 768
#define HDIM 3072

typedef unsigned short u16;
typedef __bf16 bf16x8 __attribute__((ext_vector_type(8)));
typedef float f32x4 __attribute__((ext_vector_type(4)));

__device__ __forceinline__ float b2f(u16 u) {
    union { unsigned i; float f; } v; v.i = ((unsigned)u) << 16; return v.f;
}
__device__ __forceinline__ u16 f2b(float f) {
    union { float f; unsigned i; } v; v.f = f;
    unsigned r = (v.i + 0x7FFFu + ((v.i >> 16) & 1u)) >> 16;
    return (u16)r;
}
__device__ __forceinline__ float gelu_f(float v) {
    return 0.5f * v * (1.f + erff(v * 0.70710678118654752f));
}
__device__ __forceinline__ void gl_lds16(const void* g, void* l) {
    __builtin_amdgcn_global_load_lds(
        (__attribute__((address_space(1))) void*)(g),
        (__attribute__((address_space(3))) void*)(l), 16, 0, 0);
}

// ---------- fp32 -> bf16 convert (vectorized) ----------
__global__ __launch_bounds__(256) void cvt_bf16(const float4* __restrict__ s,
                                                ushort4* __restrict__ d, int n4) {
    int i = blockIdx.x * 256 + threadIdx.x;
    if (i < n4) {
        float4 v = s[i];
        ushort4 o;
        o.x = f2b(v.x); o.y = f2b(v.y); o.z = f2b(v.z); o.w = f2b(v.w);
        d[i] = o;
    }
}

__global__ void pack_bias3(const float* __restrict__ a, const float* __restrict__ b,
                           const float* __restrict__ c, float* __restrict__ o) {
    int i = blockIdx.x * 256 + threadIdx.x;
    if (i < DIM) { o[i] = a[i]; o[i + DIM] = b[i]; o[i + 2 * DIM] = c[i]; }
}

// ---------- LayerNorm (ddof=1, eps added to std), wave per row ----------
__global__ __launch_bounds__(256) void ln_rows(const float* __restrict__ x, u16* __restrict__ xn,
                                               const float* __restrict__ g, const float* __restrict__ b) {
    int row = blockIdx.x * 4 + (threadIdx.x >> 6);
    int lane = threadIdx.x & 63;
    const float* xr = x + (size_t)row * DIM + lane * 12;
    float v[12];
#pragma unroll
    for (int i = 0; i < 3; ++i) {
        float4 t = ((const float4*)xr)[i];
        v[i * 4 + 0] = t.x; v[i * 4 + 1] = t.y; v[i * 4 + 2] = t.z; v[i * 4 + 3] = t.w;
    }
    float s = 0.f, ss = 0.f;
#pragma unroll
    for (int i = 0; i < 12; ++i) { s += v[i]; ss += v[i] * v[i]; }
#pragma unroll
    for (int o = 32; o; o >>= 1) { s += __shfl_xor(s, o); ss += __shfl_xor(ss, o); }
    float mean = s * (1.f / DIM);
    float var = (ss - (float)DIM * mean * mean) * (1.f / (DIM - 1));
    float denom = sqrtf(var) + 1e-6f;
    float sc = g[0] / denom, bb = b[0] - mean * sc;
    u16* outp = xn + (size_t)row * DIM + lane * 12;
#pragma unroll
    for (int i = 0; i < 3; ++i) {
        ushort4 o;
        o.x = f2b(v[i * 4 + 0] * sc + bb);
        o.y = f2b(v[i * 4 + 1] * sc + bb);
        o.z = f2b(v[i * 4 + 2] * sc + bb);
        o.w = f2b(v[i * 4 + 3] * sc + bb);
        ((ushort4*)outp)[i] = o;
    }
}

// ---------- GEMM: C[M,N] = A[M,K] @ B[N,K]^T  (bf16 in, fp32 acc) ----------
// EPI 0: C=acc+bias -> bf16 store   (QKV)
// EPI 1: C=gelu(acc+bias) -> bf16   (MLP up)
// EPI 2: C=acc+bias+resid -> f32    (MLP down + residual)
template <int EPI>
__global__ __launch_bounds__(256)
void gemm_bt(const u16* __restrict__ A, const u16* __restrict__ B,
             const float* __restrict__ bias, const float* __restrict__ resid,
             u16* __restrict__ Cb, float* __restrict__ Cf, int N, int K) {
    __shared__ __align__(16) u16 As[128 * 32];
    __shared__ __align__(16) u16 Bs[128 * 32];
    const int tid = threadIdx.x;
    const int row0 = blockIdx.x * 128, col0 = blockIdx.y * 128;
    const int lane = tid & 63, wave = tid >> 6;
    const int wm = (wave >> 1) * 64, wn = (wave & 1) * 64;
    const int la = lane & 15, qd = lane >> 4;
    f32x4 acc[4][4] = {};

    const int srow = tid >> 2, sko = (tid & 3) * 8;
    const u16* Ag = A + (size_t)(row0 + srow) * K + sko;
    const u16* Bg = B + (size_t)(col0 + srow) * K + sko;
    const size_t s64 = (size_t)64 * K;
    u16* AsW0 = &As[(size_t)(tid & ~63) * 8];
    u16* AsW1 = AsW0 + 2048;
    u16* BsW0 = &Bs[(size_t)(tid & ~63) * 8];
    u16* BsW1 = BsW0 + 2048;
    const u16* Ard = &As[(wm + la) * 32 + qd * 8];
    const u16* Brd = &Bs[(wn + la) * 32 + qd * 8];

    for (int kb = 0; kb < K; kb += 32) {
        gl_lds16(Ag, AsW0);
        gl_lds16(Ag + s64, AsW1);
        gl_lds16(Bg, BsW0);
        gl_lds16(Bg + s64, BsW1);
        Ag += 32; Bg += 32;
        __syncthreads();
        bf16x8 af[4], bf[4];
#pragma unroll
        for (int i = 0; i < 4; ++i) af[i] = *(const bf16x8*)(Ard + i * 512);
#pragma unroll
        for (int j = 0; j < 4; ++j) bf[j] = *(const bf16x8*)(Brd + j * 512);
#pragma unroll
        for (int i = 0; i < 4; ++i)
#pragma unroll
            for (int j = 0; j < 4; ++j)
                acc[i][j] = __builtin_amdgcn_mfma_f32_16x16x32_bf16(af[i], bf[j], acc[i][j], 0, 0, 0);
        __syncthreads();
    }
    const int rb = row0 + wm + qd * 4;
    const int cb = col0 + wn + la;
#pragma unroll
    for (int j = 0; j < 4; ++j) {
        const int col = cb + j * 16;
        const float bv = bias[col];
#pragma unroll
        for (int i = 0; i < 4; ++i) {
#pragma unroll
            for (int r = 0; r < 4; ++r) {
                const int row = rb + i * 16 + r;
                float v = acc[i][j][r] + bv;
                size_t idx = (size_t)row * N + col;
                if (EPI == 1) v = gelu_f(v);
                if (EPI == 2) Cf[idx] = v + resid[idx];
                else          Cb[idx] = f2b(v);
            }
        }
    }
}

// ---------- attention (8-token groups) + residual + LN2, block per group ----------
__global__ __launch_bounds__(256)
void attn_ln(const u16* __restrict__ qkv, const float* __restrict__ x,
             float* __restrict__ x1, u16* __restrict__ xn2,
             const float* __restrict__ g, const float* __restrict__ b) {
    __shared__ __align__(16) u16 sq[8 * 2304];
    __shared__ float sw[64];
    const int tid = threadIdx.x;
    const size_t gbase = (size_t)blockIdx.x * (8 * 2304);
    const uint4* src = (const uint4*)(qkv + gbase);
    uint4* dst = (uint4*)sq;
#pragma unroll
    for (int i = 0; i < 9; ++i) dst[tid + i * 256] = src[tid + i * 256];
    __syncthreads();
    const int wave = tid >> 6, lane = tid & 63;
#pragma unroll 1
    for (int p = wave * 16; p < wave * 16 + 16; ++p) {
        const u16* qr = sq + (p >> 3) * 2304;
        const u16* kr = sq + (p & 7) * 2304 + 768;
        float s = 0.f;
#pragma unroll
        for (int i = 0; i < 12; ++i) { int d = lane + i * 64; s += b2f(qr[d]) * b2f(kr[d]); }
#pragma unroll
        for (int o = 32; o; o >>= 1) s += __shfl_xor(s, o);
        if (lane == 0) sw[p] = s;
    }
    __syncthreads();
    if (tid < 8) {
        const float scl = 0.03608439182435161f; // 1/sqrt(768)
        float e[8]; float m = -1e30f;
#pragma unroll
        for (int j = 0; j < 8; ++j) m = fmaxf(m, sw[tid * 8 + j]);
        float sum = 0.f;
#pragma unroll
        for (int j = 0; j < 8; ++j) { e[j] = expf((sw[tid * 8 + j] - m) * scl); sum += e[j]; }
        float inv = 1.f / sum;
#pragma unroll
        for (int j = 0; j < 8; ++j) sw[tid * 8 + j] = e[j] * inv;
    }
    __syncthreads();
    const int h = tid >> 5, li = tid & 31;
    float w[8];
#pragma unroll
    for (int kk = 0; kk < 8; ++kk) w[kk] = sw[h * 8 + kk];
    const size_t trow = (size_t)blockIdx.x * 8 + h;
    const float* xr = x + trow * DIM;
    float* x1r = x1 + trow * DIM;
    u16* xnr = xn2 + trow * DIM;
    float xv[24], s = 0.f, ss = 0.f;
#pragma unroll
    for (int i = 0; i < 24; ++i) {
        int d = li + i * 32;
        float o = 0.f;
#pragma unroll
        for (int kk = 0; kk < 8; ++kk) o += w[kk] * b2f(sq[kk * 2304 + 1536 + d]);
        float val = o + xr[d];
        x1r[d] = val;
        xv[i] = val; s += val; ss += val * val;
    }
#pragma unroll
    for (int o2 = 16; o2; o2 >>= 1) { s += __shfl_xor(s, o2); ss += __shfl_xor(ss, o2); }
    float mean = s * (1.f / 768.f);
    float var = (ss - 768.f * mean * mean) * (1.f / 767.f);
    float denom = sqrtf(var) + 1e-6f;
    float sc = g[0] / denom, bb = b[0] - mean * sc;
#pragma unroll
    for (int i = 0; i < 24; ++i) xnr[li + i * 32] = f2b(xv[i] * sc + bb);
}

extern "C" void kernel_launch(void* const* d_in, const int* in_sizes, int n_in,
                              void* d_out, int out_size, void* d_ws, size_t ws_size,
                              hipStream_t stream) {
    (void)n_in; (void)out_size; (void)ws_size;
    const float* x    = (const float*)d_in[0];
    const float* wq_w = (const float*)d_in[1];
    const float* wq_b = (const float*)d_in[2];
    const float* wk_w = (const float*)d_in[3];
    const float* wk_b = (const float*)d_in[4];
    const float* wv_w = (const float*)d_in[5];
    const float* wv_b = (const float*)d_in[6];
    const float* d1_w = (const float*)d_in[7];
    const float* d1_b = (const float*)d_in[8];
    const float* d2_w = (const float*)d_in[9];
    const float* d2_b = (const float*)d_in[10];
    const float* g1 = (const float*)d_in[11];
    const float* b1 = (const float*)d_in[12];
    const float* g2 = (const float*)d_in[13];
    const float* b2 = (const float*)d_in[14];
    float* out = (float*)d_out;
    char* ws = (char*)d_ws;

    const int T = in_sizes[0] / DIM;  // 16384

    // ws layout (bytes):
    u16*   w_qkv = (u16*)(ws);                    // [2304][768] bf16   3,538,944
    u16*   w_d1  = (u16*)(ws + 3538944);          // [3072][768] bf16   4,718,592
    u16*   w_d2  = (u16*)(ws + 8257536);          // [768][3072] bf16   4,718,592
    float* b_qkv = (float*)(ws + 12976128);       // [2304] f32             9,216
    u16*   xn    = (u16*)(ws + 12985344);         // [T][768] bf16     25,165,824 (xn1 then xn2)
    float* x1    = (float*)(ws + 38151168);       // [T][768] f32      50,331,648
    u16*   qkv   = (u16*)(ws + 88482816);         // [T][2304] bf16 / reused as h [T][3072] bf16
    u16*   hbuf  = qkv;

    cvt_bf16<<<576, 256, 0, stream>>>((const float4*)wq_w, (ushort4*)w_qkv, 147456);
    cvt_bf16<<<576, 256, 0, stream>>>((const float4*)wk_w, (ushort4*)(w_qkv + 589824), 147456);
    cvt_bf16<<<576, 256, 0, stream>>>((const float4*)wv_w, (ushort4*)(w_qkv + 1179648), 147456);
    cvt_bf16<<<2304, 256, 0, stream>>>((const float4*)d1_w, (ushort4*)w_d1, 589824);
    cvt_bf16<<<2304, 256, 0, stream>>>((const float4*)d2_w, (ushort4*)w_d2, 589824);
    pack_bias3<<<3, 256, 0, stream>>>(wq_b, wk_b, wv_b, b_qkv);

    ln_rows<<<T / 4, 256, 0, stream>>>(x, xn, g1, b1);
    gemm_bt<0><<<dim3(T / 128, 18), 256, 0, stream>>>(xn, w_qkv, b_qkv, nullptr, qkv, nullptr, 2304, 768);
    attn_ln<<<T / 8, 256, 0, stream>>>(qkv, x, x1, xn, g2, b2);
    gemm_bt<1><<<dim3(T / 128, 24), 256, 0, stream>>>(xn, w_d1, d1_b, nullptr, hbuf, nullptr, 3072, 768);
    gemm_bt<2><<<dim3(T / 128, 6), 256, 0, stream>>>(hbuf, w_d2, d2_b, x1, nullptr, out, 768, 3072);
}

// Round 2
// 517.869 us; speedup vs baseline: 1.1681x; 1.1681x over previous
//
#include <hip/hip_runtime.h>
#include <stdint.h>

#define DIM 768
#define HDIM 3072

typedef unsigned short u16;
typedef __bf16 bf16x8 __attribute__((ext_vector_type(8)));
typedef float f32x4 __attribute__((ext_vector_type(4)));

__device__ __forceinline__ float b2f(u16 u) {
    union { unsigned i; float f; } v; v.i = ((unsigned)u) << 16; return v.f;
}
__device__ __forceinline__ u16 f2b(float f) {
    union { float f; unsigned i; } v; v.f = f;
    unsigned r = (v.i + 0x7FFFu + ((v.i >> 16) & 1u)) >> 16;
    return (u16)r;
}
// tanh-form GELU via v_exp_f32 / v_rcp_f32 (max abs err vs exact ~1e-3)
__device__ __forceinline__ float gelu_f(float v) {
    float u = v * (1.5957691216f + 0.07135481627f * v * v);
    float e = __builtin_amdgcn_exp2f(-1.442695041f * u);
    return v * __builtin_amdgcn_rcpf(1.0f + e);
}
__device__ __forceinline__ void gl_lds16(const void* g, void* l) {
    __builtin_amdgcn_global_load_lds(
        (__attribute__((address_space(1))) void*)(g),
        (__attribute__((address_space(3))) void*)(l), 16, 0, 0);
}

// ---------- fp32 -> bf16 convert (vectorized) ----------
__global__ __launch_bounds__(256) void cvt_bf16(const float4* __restrict__ s,
                                                ushort4* __restrict__ d, int n4) {
    int i = blockIdx.x * 256 + threadIdx.x;
    if (i < n4) {
        float4 v = s[i];
        ushort4 o;
        o.x = f2b(v.x); o.y = f2b(v.y); o.z = f2b(v.z); o.w = f2b(v.w);
        d[i] = o;
    }
}

__global__ void pack_bias3(const float* __restrict__ a, const float* __restrict__ b,
                           const float* __restrict__ c, float* __restrict__ o) {
    int i = blockIdx.x * 256 + threadIdx.x;
    if (i < DIM) { o[i] = a[i]; o[i + DIM] = b[i]; o[i + 2 * DIM] = c[i]; }
}

// ---------- LayerNorm (ddof=1, eps added to std), wave per row ----------
__global__ __launch_bounds__(256) void ln_rows(const float* __restrict__ x, u16* __restrict__ xn,
                                               const float* __restrict__ g, const float* __restrict__ b) {
    int row = blockIdx.x * 4 + (threadIdx.x >> 6);
    int lane = threadIdx.x & 63;
    const float* xr = x + (size_t)row * DIM + lane * 12;
    float v[12];
#pragma unroll
    for (int i = 0; i < 3; ++i) {
        float4 t = ((const float4*)xr)[i];
        v[i * 4 + 0] = t.x; v[i * 4 + 1] = t.y; v[i * 4 + 2] = t.z; v[i * 4 + 3] = t.w;
    }
    float s = 0.f, ss = 0.f;
#pragma unroll
    for (int i = 0; i < 12; ++i) { s += v[i]; ss += v[i] * v[i]; }
#pragma unroll
    for (int o = 32; o; o >>= 1) { s += __shfl_xor(s, o); ss += __shfl_xor(ss, o); }
    float mean = s * (1.f / DIM);
    float var = (ss - (float)DIM * mean * mean) * (1.f / (DIM - 1));
    float denom = sqrtf(var) + 1e-6f;
    float sc = g[0] / denom, bb = b[0] - mean * sc;
    u16* outp = xn + (size_t)row * DIM + lane * 12;
#pragma unroll
    for (int i = 0; i < 3; ++i) {
        ushort4 o;
        o.x = f2b(v[i * 4 + 0] * sc + bb);
        o.y = f2b(v[i * 4 + 1] * sc + bb);
        o.z = f2b(v[i * 4 + 2] * sc + bb);
        o.w = f2b(v[i * 4 + 3] * sc + bb);
        ((ushort4*)outp)[i] = o;
    }
}

// ---------- GEMM: C[M,N] = A[M,K] @ B[N,K]^T  (bf16 in, fp32 acc) ----------
// BK=64, XOR-swizzled LDS (chunk position p of row r holds global chunk p^(r&7)).
// EPI 0: C=acc+bias -> bf16 store   (QKV)
// EPI 1: C=gelu(acc+bias) -> bf16   (MLP up)
// EPI 2: C=acc+bias+resid -> f32    (MLP down + residual)
template <int EPI>
__global__ __launch_bounds__(256)
void gemm_bt(const u16* __restrict__ A, const u16* __restrict__ B,
             const float* __restrict__ bias, const float* __restrict__ resid,
             u16* __restrict__ Cb, float* __restrict__ Cf, int N, int K) {
    __shared__ __align__(16) u16 As[128 * 64];
    __shared__ __align__(16) u16 Bs[128 * 64];
    const int tid = threadIdx.x;
    const int row0 = blockIdx.x * 128, col0 = blockIdx.y * 128;
    const int lane = tid & 63, wave = tid >> 6;
    const int wm = (wave >> 1) * 64, wn = (wave & 1) * 64;
    const int la = lane & 15, qd = lane >> 4;
    f32x4 acc[4][4] = {};

    // staging: lane l -> row (l>>3) within its wave's 8-row group, LDS chunk (l&7);
    // source chunk is (l&7)^(srow&7) so LDS[r][p] = global[r][p^(r&7)]
    const int srow = lane >> 3;
    const int schunk = (lane & 7) ^ srow;
    const u16* Ag = A + (size_t)(row0 + wave * 8 + srow) * K + schunk * 8;
    const u16* Bg = B + (size_t)(col0 + wave * 8 + srow) * K + schunk * 8;
    const size_t s32 = (size_t)32 * K;
    u16* AsW = &As[wave * 512];
    u16* BsW = &Bs[wave * 512];

    const int x7 = la & 7;  // read-side swizzle key (row & 7 == la & 7)

    for (int kb = 0; kb < K; kb += 64) {
#pragma unroll
        for (int i = 0; i < 4; ++i) {
            gl_lds16(Ag + i * s32, AsW + i * 2048);
            gl_lds16(Bg + i * s32, BsW + i * 2048);
        }
        Ag += 64; Bg += 64;
        __syncthreads();
#pragma unroll
        for (int ks = 0; ks < 2; ++ks) {
            const int cp = ((ks * 4 + qd) ^ x7) * 8;
            bf16x8 af[4], bfr[4];
#pragma unroll
            for (int i = 0; i < 4; ++i)
                af[i] = *(const bf16x8*)(&As[(wm + i * 16 + la) * 64 + cp]);
#pragma unroll
            for (int j = 0; j < 4; ++j)
                bfr[j] = *(const bf16x8*)(&Bs[(wn + j * 16 + la) * 64 + cp]);
#pragma unroll
            for (int i = 0; i < 4; ++i)
#pragma unroll
                for (int j = 0; j < 4; ++j)
                    acc[i][j] = __builtin_amdgcn_mfma_f32_16x16x32_bf16(af[i], bfr[j], acc[i][j], 0, 0, 0);
        }
        __syncthreads();
    }
    const int rb = row0 + wm + qd * 4;
    const int cb = col0 + wn + la;
#pragma unroll
    for (int j = 0; j < 4; ++j) {
        const int col = cb + j * 16;
        const float bv = bias[col];
#pragma unroll
        for (int i = 0; i < 4; ++i) {
#pragma unroll
            for (int r = 0; r < 4; ++r) {
                const int row = rb + i * 16 + r;
                float v = acc[i][j][r] + bv;
                size_t idx = (size_t)row * N + col;
                if (EPI == 1) v = gelu_f(v);
                if (EPI == 2) Cf[idx] = v + resid[idx];
                else          Cb[idx] = f2b(v);
            }
        }
    }
}

// ---------- attention (8-token groups) + residual + LN2, block per group ----------
__global__ __launch_bounds__(256)
void attn_ln(const u16* __restrict__ qkv, const float* __restrict__ x,
             float* __restrict__ x1, u16* __restrict__ xn2,
             const float* __restrict__ g, const float* __restrict__ b) {
    __shared__ __align__(16) u16 sq[8 * 2304];
    __shared__ float sw[64];
    const int tid = threadIdx.x;
    const size_t gbase = (size_t)blockIdx.x * (8 * 2304);
    const uint4* src = (const uint4*)(qkv + gbase);
    uint4* dst = (uint4*)sq;
#pragma unroll
    for (int i = 0; i < 9; ++i) dst[tid + i * 256] = src[tid + i * 256];
    __syncthreads();
    const int wave = tid >> 6, lane = tid & 63;
#pragma unroll 1
    for (int p = wave * 16; p < wave * 16 + 16; ++p) {
        const u16* qr = sq + (p >> 3) * 2304;
        const u16* kr = sq + (p & 7) * 2304 + 768;
        float s = 0.f;
#pragma unroll
        for (int i = 0; i < 12; ++i) { int d = lane + i * 64; s += b2f(qr[d]) * b2f(kr[d]); }
#pragma unroll
        for (int o = 32; o; o >>= 1) s += __shfl_xor(s, o);
        if (lane == 0) sw[p] = s;
    }
    __syncthreads();
    if (tid < 8) {
        const float scl = 0.03608439182435161f; // 1/sqrt(768)
        float e[8]; float m = -1e30f;
#pragma unroll
        for (int j = 0; j < 8; ++j) m = fmaxf(m, sw[tid * 8 + j]);
        float sum = 0.f;
#pragma unroll
        for (int j = 0; j < 8; ++j) { e[j] = expf((sw[tid * 8 + j] - m) * scl); sum += e[j]; }
        float inv = 1.f / sum;
#pragma unroll
        for (int j = 0; j < 8; ++j) sw[tid * 8 + j] = e[j] * inv;
    }
    __syncthreads();
    const int h = tid >> 5, li = tid & 31;
    float w[8];
#pragma unroll
    for (int kk = 0; kk < 8; ++kk) w[kk] = sw[h * 8 + kk];
    const size_t trow = (size_t)blockIdx.x * 8 + h;
    const float* xr = x + trow * DIM;
    float* x1r = x1 + trow * DIM;
    u16* xnr = xn2 + trow * DIM;
    float xv[24], s = 0.f, ss = 0.f;
#pragma unroll
    for (int i = 0; i < 24; ++i) {
        int d = li + i * 32;
        float o = 0.f;
#pragma unroll
        for (int kk = 0; kk < 8; ++kk) o += w[kk] * b2f(sq[kk * 2304 + 1536 + d]);
        float val = o + xr[d];
        x1r[d] = val;
        xv[i] = val; s += val; ss += val * val;
    }
#pragma unroll
    for (int o2 = 16; o2; o2 >>= 1) { s += __shfl_xor(s, o2); ss += __shfl_xor(ss, o2); }
    float mean = s * (1.f / 768.f);
    float var = (ss - 768.f * mean * mean) * (1.f / 767.f);
    float denom = sqrtf(var) + 1e-6f;
    float sc = g[0] / denom, bb = b[0] - mean * sc;
#pragma unroll
    for (int i = 0; i < 24; ++i) xnr[li + i * 32] = f2b(xv[i] * sc + bb);
}

extern "C" void kernel_launch(void* const* d_in, const int* in_sizes, int n_in,
                              void* d_out, int out_size, void* d_ws, size_t ws_size,
                              hipStream_t stream) {
    (void)n_in; (void)out_size; (void)ws_size;
    const float* x    = (const float*)d_in[0];
    const float* wq_w = (const float*)d_in[1];
    const float* wq_b = (const float*)d_in[2];
    const float* wk_w = (const float*)d_in[3];
    const float* wk_b = (const float*)d_in[4];
    const float* wv_w = (const float*)d_in[5];
    const float* wv_b = (const float*)d_in[6];
    const float* d1_w = (const float*)d_in[7];
    const float* d1_b = (const float*)d_in[8];
    const float* d2_w = (const float*)d_in[9];
    const float* d2_b = (const float*)d_in[10];
    const float* g1 = (const float*)d_in[11];
    const float* b1 = (const float*)d_in[12];
    const float* g2 = (const float*)d_in[13];
    const float* b2 = (const float*)d_in[14];
    float* out = (float*)d_out;
    char* ws = (char*)d_ws;

    const int T = in_sizes[0] / DIM;  // 16384

    // ws layout (bytes):
    u16*   w_qkv = (u16*)(ws);                    // [2304][768] bf16   3,538,944
    u16*   w_d1  = (u16*)(ws + 3538944);          // [3072][768] bf16   4,718,592
    u16*   w_d2  = (u16*)(ws + 8257536);          // [768][3072] bf16   4,718,592
    float* b_qkv = (float*)(ws + 12976128);       // [2304] f32             9,216
    u16*   xn    = (u16*)(ws + 12985344);         // [T][768] bf16     25,165,824 (xn1 then xn2)
    float* x1    = (float*)(ws + 38151168);       // [T][768] f32      50,331,648
    u16*   qkv   = (u16*)(ws + 88482816);         // [T][2304] bf16 / reused as h [T][3072] bf16
    u16*   hbuf  = qkv;

    cvt_bf16<<<576, 256, 0, stream>>>((const float4*)wq_w, (ushort4*)w_qkv, 147456);
    cvt_bf16<<<576, 256, 0, stream>>>((const float4*)wk_w, (ushort4*)(w_qkv + 589824), 147456);
    cvt_bf16<<<576, 256, 0, stream>>>((const float4*)wv_w, (ushort4*)(w_qkv + 1179648), 147456);
    cvt_bf16<<<2304, 256, 0, stream>>>((const float4*)d1_w, (ushort4*)w_d1, 589824);
    cvt_bf16<<<2304, 256, 0, stream>>>((const float4*)d2_w, (ushort4*)w_d2, 589824);
    pack_bias3<<<3, 256, 0, stream>>>(wq_b, wk_b, wv_b, b_qkv);

    ln_rows<<<T / 4, 256, 0, stream>>>(x, xn, g1, b1);
    gemm_bt<0><<<dim3(T / 128, 18), 256, 0, stream>>>(xn, w_qkv, b_qkv, nullptr, qkv, nullptr, 2304, 768);
    attn_ln<<<T / 8, 256, 0, stream>>>(qkv, x, x1, xn, g2, b2);
    gemm_bt<1><<<dim3(T / 128, 24), 256, 0, stream>>>(xn, w_d1, d1_b, nullptr, hbuf, nullptr, 3072, 768);
    gemm_bt<2><<<dim3(T / 128, 6), 256, 0, stream>>>(hbuf, w_d2, d2_b, x1, nullptr, out, 768, 3072);
}

// Round 3
// 402.348 us; speedup vs baseline: 1.5035x; 1.2871x over previous
//
#include <hip/hip_runtime.h>
#include <stdint.h>

#define DIM 768
#define HDIM 3072

typedef unsigned short u16;
typedef unsigned char u8;
typedef __bf16 bf16x8 __attribute__((ext_vector_type(8)));
typedef float f32x4 __attribute__((ext_vector_type(4)));
typedef float f32x16 __attribute__((ext_vector_type(16)));
typedef int i32x8 __attribute__((ext_vector_type(8)));

__device__ __forceinline__ float b2f(u16 u) {
    union { unsigned i; float f; } v; v.i = ((unsigned)u) << 16; return v.f;
}
__device__ __forceinline__ u16 f2b(float f) {
    union { float f; unsigned i; } v; v.f = f;
    unsigned r = (v.i + 0x7FFFu + ((v.i >> 16) & 1u)) >> 16;
    return (u16)r;
}
// tanh-form GELU via v_exp_f32 / v_rcp_f32 (max abs err vs exact ~1e-3)
__device__ __forceinline__ float gelu_f(float v) {
    float u = v * (1.5957691216f + 0.07135481627f * v * v);
    float e = __builtin_amdgcn_exp2f(-1.442695041f * u);
    return v * __builtin_amdgcn_rcpf(1.0f + e);
}
__device__ __forceinline__ void gl_lds16(const void* g, void* l) {
    __builtin_amdgcn_global_load_lds(
        (__attribute__((address_space(1))) void*)(g),
        (__attribute__((address_space(3))) void*)(l), 16, 0, 0);
}

// ---------- fp32 -> bf16 convert ----------
__global__ __launch_bounds__(256) void cvt_bf16(const float4* __restrict__ s,
                                                ushort4* __restrict__ d, int n4) {
    int i = blockIdx.x * 256 + threadIdx.x;
    if (i < n4) {
        float4 v = s[i];
        ushort4 o;
        o.x = f2b(v.x); o.y = f2b(v.y); o.z = f2b(v.z); o.w = f2b(v.w);
        d[i] = o;
    }
}

// ---------- fp32 -> fp8 e4m3 convert (4 floats -> 1 dword) ----------
__global__ __launch_bounds__(256) void cvt_fp8(const float4* __restrict__ s,
                                               unsigned* __restrict__ d, int n4) {
    int i = blockIdx.x * 256 + threadIdx.x;
    if (i < n4) {
        float4 v = s[i];
        int p = __builtin_amdgcn_cvt_pk_fp8_f32(v.x, v.y, 0, false);
        p = __builtin_amdgcn_cvt_pk_fp8_f32(v.z, v.w, p, true);
        d[i] = (unsigned)p;
    }
}

__global__ void pack_bias3(const float* __restrict__ a, const float* __restrict__ b,
                           const float* __restrict__ c, float* __restrict__ o) {
    int i = blockIdx.x * 256 + threadIdx.x;
    if (i < DIM) { o[i] = a[i]; o[i + DIM] = b[i]; o[i + 2 * DIM] = c[i]; }
}

// ---------- LayerNorm (ddof=1, eps on std), wave per row, fp8 output ----------
__global__ __launch_bounds__(256) void ln_rows_f8(const float* __restrict__ x, u8* __restrict__ xn,
                                                  const float* __restrict__ g, const float* __restrict__ b) {
    int row = blockIdx.x * 4 + (threadIdx.x >> 6);
    int lane = threadIdx.x & 63;
    const float* xr = x + (size_t)row * DIM + lane * 12;
    float v[12];
#pragma unroll
    for (int i = 0; i < 3; ++i) {
        float4 t = ((const float4*)xr)[i];
        v[i * 4 + 0] = t.x; v[i * 4 + 1] = t.y; v[i * 4 + 2] = t.z; v[i * 4 + 3] = t.w;
    }
    float s = 0.f, ss = 0.f;
#pragma unroll
    for (int i = 0; i < 12; ++i) { s += v[i]; ss += v[i] * v[i]; }
#pragma unroll
    for (int o = 32; o; o >>= 1) { s += __shfl_xor(s, o); ss += __shfl_xor(ss, o); }
    float mean = s * (1.f / DIM);
    float var = (ss - (float)DIM * mean * mean) * (1.f / (DIM - 1));
    float denom = sqrtf(var) + 1e-6f;
    float sc = g[0] / denom, bb = b[0] - mean * sc;
    unsigned* outp = (unsigned*)(xn + (size_t)row * DIM + lane * 12);
#pragma unroll
    for (int i = 0; i < 3; ++i) {
        int p = __builtin_amdgcn_cvt_pk_fp8_f32(v[i * 4 + 0] * sc + bb, v[i * 4 + 1] * sc + bb, 0, false);
        p = __builtin_amdgcn_cvt_pk_fp8_f32(v[i * 4 + 2] * sc + bb, v[i * 4 + 3] * sc + bb, p, true);
        outp[i] = (unsigned)p;
    }
}

// ---------- fp8 GEMM: C[M,N] = A[M,K] @ B[N,K]^T, MX-scaled MFMA w/ unit scales ----------
// BK=128, 128x128 tile, 4 waves each 64x64 (2x2 of 32x32x64 frags).
// XOR-16B-chunk swizzle: LDS[r][chunk p] = global[r][chunk p ^ (r&7)].
// EPI 0: acc+bias -> bf16   (QKV)
// EPI 2: acc+bias+resid -> f32  (MLP down + residual)
template <int EPI>
__global__ __launch_bounds__(256)
void gemm_f8(const u8* __restrict__ A, const u8* __restrict__ B,
             const float* __restrict__ bias, const float* __restrict__ resid,
             u16* __restrict__ Cb, float* __restrict__ Cf, int N, int K) {
    __shared__ __align__(16) u8 As[128 * 128];
    __shared__ __align__(16) u8 Bs[128 * 128];
    const int tid = threadIdx.x, lane = tid & 63, wave = tid >> 6;
    const int row0 = blockIdx.x * 128, col0 = blockIdx.y * 128;
    const int wm = (wave >> 1) * 64, wn = (wave & 1) * 64;
    f32x16 acc[2][2] = {};

    // staging: wave w round i covers rows w*8 + i*32 + (lane>>3), chunk lane&7 (swizzled src)
    const int srow = lane >> 3;
    const int schunk = ((lane & 7) ^ srow) * 16;
    const u8* Ag = A + (size_t)(row0 + wave * 8 + srow) * K + schunk;
    const u8* Bg = B + (size_t)(col0 + wave * 8 + srow) * K + schunk;
    const size_t s32 = (size_t)32 * K;
    u8* AsW = As + wave * 1024;
    u8* BsW = Bs + wave * 1024;

    const int r31 = lane & 31, khalf = lane >> 5;

    for (int kb = 0; kb < K; kb += 128) {
#pragma unroll
        for (int i = 0; i < 4; ++i) {
            gl_lds16(Ag + i * s32, AsW + i * 4096);
            gl_lds16(Bg + i * s32, BsW + i * 4096);
        }
        Ag += 128; Bg += 128;
        __syncthreads();
#pragma unroll
        for (int ks = 0; ks < 2; ++ks) {
            const int c0 = ks * 4 + khalf * 2;  // 16B chunk index (even)
            union { i32x8 v; uint4 q[2]; } af[2], bfr[2];
#pragma unroll
            for (int ib = 0; ib < 2; ++ib) {
                const int r = wm + ib * 32 + r31;
                const u8* base = As + r * 128;
                const int x7 = (r & 7);
                af[ib].q[0] = *(const uint4*)(base + ((c0 ^ x7) * 16));
                af[ib].q[1] = *(const uint4*)(base + (((c0 + 1) ^ x7) * 16));
            }
#pragma unroll
            for (int jb = 0; jb < 2; ++jb) {
                const int r = wn + jb * 32 + r31;
                const u8* base = Bs + r * 128;
                const int x7 = (r & 7);
                bfr[jb].q[0] = *(const uint4*)(base + ((c0 ^ x7) * 16));
                bfr[jb].q[1] = *(const uint4*)(base + (((c0 + 1) ^ x7) * 16));
            }
#pragma unroll
            for (int ib = 0; ib < 2; ++ib)
#pragma unroll
                for (int jb = 0; jb < 2; ++jb)
                    acc[ib][jb] = __builtin_amdgcn_mfma_scale_f32_32x32x64_f8f6f4(
                        af[ib].v, bfr[jb].v, acc[ib][jb], 0, 0,
                        0, 0x7F7F7F7F, 0, 0x7F7F7F7F);  // unit E8M0 scales
        }
        __syncthreads();
    }
    // C/D 32x32 layout: col=lane&31, row=(reg&3)+8*(reg>>2)+4*(lane>>5)
    const int colq = col0 + wn + r31;
    const int rbase = row0 + wm + 4 * khalf;
#pragma unroll
    for (int jb = 0; jb < 2; ++jb) {
        const int col = colq + jb * 32;
        const float bv = bias[col];
#pragma unroll
        for (int ib = 0; ib < 2; ++ib) {
#pragma unroll
            for (int reg = 0; reg < 16; ++reg) {
                const int row = rbase + ib * 32 + (reg & 3) + 8 * (reg >> 2);
                float v = acc[ib][jb][reg] + bv;
                size_t idx = (size_t)row * N + col;
                if (EPI == 2) Cf[idx] = v + resid[idx];
                else          Cb[idx] = f2b(v);
            }
        }
    }
}

// ---------- bf16 GEMM (MLP up): gelu epilogue, fp8 output ----------
__global__ __launch_bounds__(256)
void gemm_up(const u16* __restrict__ A, const u16* __restrict__ B,
             const float* __restrict__ bias, u8* __restrict__ C8, int N, int K) {
    __shared__ __align__(16) u16 As[128 * 64];
    __shared__ __align__(16) u16 Bs[128 * 64];
    const int tid = threadIdx.x;
    const int row0 = blockIdx.x * 128, col0 = blockIdx.y * 128;
    const int lane = tid & 63, wave = tid >> 6;
    const int wm = (wave >> 1) * 64, wn = (wave & 1) * 64;
    const int la = lane & 15, qd = lane >> 4;
    f32x4 acc[4][4] = {};

    const int srow = lane >> 3;
    const int schunk = (lane & 7) ^ srow;
    const u16* Ag = A + (size_t)(row0 + wave * 8 + srow) * K + schunk * 8;
    const u16* Bg = B + (size_t)(col0 + wave * 8 + srow) * K + schunk * 8;
    const size_t s32 = (size_t)32 * K;
    u16* AsW = &As[wave * 512];
    u16* BsW = &Bs[wave * 512];
    const int x7 = la & 7;

    for (int kb = 0; kb < K; kb += 64) {
#pragma unroll
        for (int i = 0; i < 4; ++i) {
            gl_lds16(Ag + i * s32, AsW + i * 2048);
            gl_lds16(Bg + i * s32, BsW + i * 2048);
        }
        Ag += 64; Bg += 64;
        __syncthreads();
#pragma unroll
        for (int ks = 0; ks < 2; ++ks) {
            const int cp = ((ks * 4 + qd) ^ x7) * 8;
            bf16x8 af[4], bfr[4];
#pragma unroll
            for (int i = 0; i < 4; ++i)
                af[i] = *(const bf16x8*)(&As[(wm + i * 16 + la) * 64 + cp]);
#pragma unroll
            for (int j = 0; j < 4; ++j)
                bfr[j] = *(const bf16x8*)(&Bs[(wn + j * 16 + la) * 64 + cp]);
#pragma unroll
            for (int i = 0; i < 4; ++i)
#pragma unroll
                for (int j = 0; j < 4; ++j)
                    acc[i][j] = __builtin_amdgcn_mfma_f32_16x16x32_bf16(af[i], bfr[j], acc[i][j], 0, 0, 0);
        }
        __syncthreads();
    }
    const int rb = row0 + wm + qd * 4;
    const int cb = col0 + wn + la;
#pragma unroll
    for (int j = 0; j < 4; ++j) {
        const int col = cb + j * 16;
        const float bv = bias[col];
#pragma unroll
        for (int i = 0; i < 4; ++i) {
#pragma unroll
            for (int r = 0; r < 4; ++r) {
                const int row = rb + i * 16 + r;
                float v = gelu_f(acc[i][j][r] + bv);
                int p = __builtin_amdgcn_cvt_pk_fp8_f32(v, v, 0, false);
                C8[(size_t)row * N + col] = (u8)(p & 0xFF);
            }
        }
    }
}

// ---------- attention (8-token groups) + residual + LN2 ----------
__global__ __launch_bounds__(256)
void attn_ln(const u16* __restrict__ qkv, const float* __restrict__ x,
             float* __restrict__ x1, u16* __restrict__ xn2,
             const float* __restrict__ g, const float* __restrict__ b) {
    __shared__ __align__(16) u16 sq[8 * 2304];
    __shared__ float sw[64];
    const int tid = threadIdx.x;
    const size_t gbase = (size_t)blockIdx.x * (8 * 2304);
    const uint4* src = (const uint4*)(qkv + gbase);
    uint4* dst = (uint4*)sq;
#pragma unroll
    for (int i = 0; i < 9; ++i) dst[tid + i * 256] = src[tid + i * 256];
    __syncthreads();
    const int wave = tid >> 6, lane = tid & 63;
#pragma unroll 1
    for (int p = wave * 16; p < wave * 16 + 16; ++p) {
        const u16* qr = sq + (p >> 3) * 2304;
        const u16* kr = sq + (p & 7) * 2304 + 768;
        float s = 0.f;
#pragma unroll
        for (int i = 0; i < 12; ++i) { int d = lane + i * 64; s += b2f(qr[d]) * b2f(kr[d]); }
#pragma unroll
        for (int o = 32; o; o >>= 1) s += __shfl_xor(s, o);
        if (lane == 0) sw[p] = s;
    }
    __syncthreads();
    if (tid < 8) {
        const float scl = 0.03608439182435161f; // 1/sqrt(768)
        float e[8]; float m = -1e30f;
#pragma unroll
        for (int j = 0; j < 8; ++j) m = fmaxf(m, sw[tid * 8 + j]);
        float sum = 0.f;
#pragma unroll
        for (int j = 0; j < 8; ++j) { e[j] = expf((sw[tid * 8 + j] - m) * scl); sum += e[j]; }
        float inv = 1.f / sum;
#pragma unroll
        for (int j = 0; j < 8; ++j) sw[tid * 8 + j] = e[j] * inv;
    }
    __syncthreads();
    const int h = tid >> 5, li = tid & 31;
    float w[8];
#pragma unroll
    for (int kk = 0; kk < 8; ++kk) w[kk] = sw[h * 8 + kk];
    const size_t trow = (size_t)blockIdx.x * 8 + h;
    const float* xr = x + trow * DIM;
    float* x1r = x1 + trow * DIM;
    u16* xnr = xn2 + trow * DIM;
    float xv[24], s = 0.f, ss = 0.f;
#pragma unroll
    for (int i = 0; i < 24; ++i) {
        int d = li + i * 32;
        float o = 0.f;
#pragma unroll
        for (int kk = 0; kk < 8; ++kk) o += w[kk] * b2f(sq[kk * 2304 + 1536 + d]);
        float val = o + xr[d];
        x1r[d] = val;
        xv[i] = val; s += val; ss += val * val;
    }
#pragma unroll
    for (int o2 = 16; o2; o2 >>= 1) { s += __shfl_xor(s, o2); ss += __shfl_xor(ss, o2); }
    float mean = s * (1.f / 768.f);
    float var = (ss - 768.f * mean * mean) * (1.f / 767.f);
    float denom = sqrtf(var) + 1e-6f;
    float sc = g[0] / denom, bb = b[0] - mean * sc;
#pragma unroll
    for (int i = 0; i < 24; ++i) xnr[li + i * 32] = f2b(xv[i] * sc + bb);
}

extern "C" void kernel_launch(void* const* d_in, const int* in_sizes, int n_in,
                              void* d_out, int out_size, void* d_ws, size_t ws_size,
                              hipStream_t stream) {
    (void)n_in; (void)out_size; (void)ws_size;
    const float* x    = (const float*)d_in[0];
    const float* wq_w = (const float*)d_in[1];
    const float* wq_b = (const float*)d_in[2];
    const float* wk_w = (const float*)d_in[3];
    const float* wk_b = (const float*)d_in[4];
    const float* wv_w = (const float*)d_in[5];
    const float* wv_b = (const float*)d_in[6];
    const float* d1_w = (const float*)d_in[7];
    const float* d1_b = (const float*)d_in[8];
    const float* d2_w = (const float*)d_in[9];
    const float* d2_b = (const float*)d_in[10];
    const float* g1 = (const float*)d_in[11];
    const float* b1 = (const float*)d_in[12];
    const float* g2 = (const float*)d_in[13];
    const float* b2 = (const float*)d_in[14];
    float* out = (float*)d_out;
    char* ws = (char*)d_ws;

    const int T = in_sizes[0] / DIM;  // 16384

    // ws layout (bytes):
    u8*    w_qkv8 = (u8*)(ws);                    // [2304][768] fp8    1,769,472
    u16*   w_d1   = (u16*)(ws + 1769472);         // [3072][768] bf16   4,718,592
    u8*    w_d28  = (u8*)(ws + 6488064);          // [768][3072] fp8    2,359,296
    float* b_qkv  = (float*)(ws + 8847360);       // [2304] f32             9,216
    u16*   xn2    = (u16*)(ws + 8856576);         // [T][768] bf16     25,165,824
    float* x1     = (float*)(ws + 34022400);      // [T][768] f32      50,331,648
    u8*    xn1_8  = (u8*)(ws + 34022400);         // [T][768] fp8 — aliases x1 (dead before attn)
    u16*   qkv    = (u16*)(ws + 84354048);        // [T][2304] bf16    75,497,472
    u8*    h8     = (u8*)(ws + 84354048);         // [T][3072] fp8 — aliases qkv (dead after attn)

    cvt_fp8<<<576, 256, 0, stream>>>((const float4*)wq_w, (unsigned*)w_qkv8, 147456);
    cvt_fp8<<<576, 256, 0, stream>>>((const float4*)wk_w, (unsigned*)(w_qkv8 + 589824), 147456);
    cvt_fp8<<<576, 256, 0, stream>>>((const float4*)wv_w, (unsigned*)(w_qkv8 + 1179648), 147456);
    cvt_bf16<<<2304, 256, 0, stream>>>((const float4*)d1_w, (ushort4*)w_d1, 589824);
    cvt_fp8<<<2304, 256, 0, stream>>>((const float4*)d2_w, (unsigned*)w_d28, 589824);
    pack_bias3<<<3, 256, 0, stream>>>(wq_b, wk_b, wv_b, b_qkv);

    ln_rows_f8<<<T / 4, 256, 0, stream>>>(x, xn1_8, g1, b1);
    gemm_f8<0><<<dim3(T / 128, 18), 256, 0, stream>>>(xn1_8, w_qkv8, b_qkv, nullptr, qkv, nullptr, 2304, 768);
    attn_ln<<<T / 8, 256, 0, stream>>>(qkv, x, x1, xn2, g2, b2);
    gemm_up<<<dim3(T / 128, 24), 256, 0, stream>>>(xn2, w_d1, d1_b, h8, 3072, 768);
    gemm_f8<2><<<dim3(T / 128, 6), 256, 0, stream>>>(h8, w_d28, d2_b, x1, nullptr, out, 768, 3072);
}